// Round 1
// baseline (1912.847 us; speedup 1.0000x reference)
//
#include <hip/hip_runtime.h>

#define M_ROWS 1000000
#define KDIM 256
#define NCOL 128
#define NSEG 1024

typedef float v4f __attribute__((ext_vector_type(4)));
typedef _Float16 v8h __attribute__((ext_vector_type(8)));

// ---------------------------------------------------------------------------
// Kernel A: scores s[i] = tanh(x[i]@W1 + b1) @ W2 + b2   via fp16 MFMA.
// W1 staged in LDS in exact 16x16x32 B-fragment order (one ds_read_b128/frag).
// Each wave: 32 rows (2 M-tiles), acc in VGPRs, fast-tanh epilogue.
// ---------------------------------------------------------------------------
__global__ __launch_bounds__(512, 4) void scores_kernel(
    const float* __restrict__ x, const float* __restrict__ W1,
    const float* __restrict__ b1, const float* __restrict__ W2,
    const float* __restrict__ b2, float* __restrict__ s, int mrows)
{
    // frag layout: wfrag[((ks*8 + n)*64 + lane)*8 + j]
    __shared__ __align__(16) _Float16 wfrag[8 * 8 * 64 * 8];  // 64 KB

    const int t = threadIdx.x;
    // Pre-swizzle W1 -> fp16 fragments. 4096 lane-slots / 512 threads = 8 each.
    for (int slot = t; slot < 4096; slot += 512) {
        const int ks = slot >> 9;
        const int n = (slot >> 6) & 7;
        const int ln = slot & 63;
        const int q = ln >> 4, mm = ln & 15;
        const int col = n * 16 + mm;
#pragma unroll
        for (int j = 0; j < 8; ++j) {
            const int k = ks * 32 + q * 8 + j;
            wfrag[slot * 8 + j] = (_Float16)W1[k * NCOL + col];
        }
    }

    const int lane = t & 63;
    const int wave = t >> 6;
    const int mm = lane & 15, q = lane >> 4;

    float b1v[8], w2v[8];
#pragma unroll
    for (int n = 0; n < 8; ++n) {
        b1v[n] = b1[n * 16 + mm];
        w2v[n] = W2[n * 16 + mm];
    }
    const float b2v = b2[0];
    __syncthreads();

    const int gw = blockIdx.x * 8 + wave;
    const int nw = gridDim.x * 8;
    const int niter = mrows / 32;

    for (int it = gw; it < niter; it += nw) {
        const int row0 = it * 32;
        v4f acc[2][8];
#pragma unroll
        for (int g = 0; g < 2; ++g)
#pragma unroll
            for (int n = 0; n < 8; ++n) acc[g][n] = (v4f){0.f, 0.f, 0.f, 0.f};

#pragma unroll
        for (int ks = 0; ks < 8; ++ks) {
            const float* xp = x + (size_t)(row0 + mm) * KDIM + ks * 32 + q * 8;
            v8h a[2];
#pragma unroll
            for (int g = 0; g < 2; ++g) {
                const v4f f0 = *(const v4f*)(xp + g * 16 * KDIM);
                const v4f f1 = *(const v4f*)(xp + g * 16 * KDIM + 4);
                a[g][0] = (_Float16)f0[0]; a[g][1] = (_Float16)f0[1];
                a[g][2] = (_Float16)f0[2]; a[g][3] = (_Float16)f0[3];
                a[g][4] = (_Float16)f1[0]; a[g][5] = (_Float16)f1[1];
                a[g][6] = (_Float16)f1[2]; a[g][7] = (_Float16)f1[3];
            }
#pragma unroll
            for (int n = 0; n < 8; ++n) {
                const v8h bfrag = *(const v8h*)&wfrag[((ks * 8 + n) * 64 + lane) * 8];
                acc[0][n] = __builtin_amdgcn_mfma_f32_16x16x32_f16(a[0], bfrag, acc[0][n], 0, 0, 0);
                acc[1][n] = __builtin_amdgcn_mfma_f32_16x16x32_f16(a[1], bfrag, acc[1][n], 0, 0, 0);
            }
        }

        // Epilogue: h -> tanh -> dot W2 -> reduce over 16 lanes of the quad.
#pragma unroll
        for (int g = 0; g < 2; ++g) {
            float part[4] = {0.f, 0.f, 0.f, 0.f};
#pragma unroll
            for (int n = 0; n < 8; ++n) {
#pragma unroll
                for (int r = 0; r < 4; ++r) {
                    const float h = acc[g][n][r] + b1v[n];
                    const float u = fminf(fmaxf(h, -15.f), 15.f);
                    const float e = __expf(2.f * u);
                    part[r] += w2v[n] * ((e - 1.f) / (e + 1.f));
                }
            }
#pragma unroll
            for (int r = 0; r < 4; ++r) {
#pragma unroll
                for (int off = 1; off < 16; off <<= 1)
                    part[r] += __shfl_xor(part[r], off, 64);
            }
            if (mm == 0) {
#pragma unroll
                for (int r = 0; r < 4; ++r)
                    s[row0 + g * 16 + q * 4 + r] = part[r] + b2v;
            }
        }
    }
}

// ---------------------------------------------------------------------------
// Kernel B1: segment boundaries via binary search (batch is sorted).
// seg_start[s] = lower_bound(batch, s); seg_start[1024] = M naturally.
// ---------------------------------------------------------------------------
__global__ void bounds_kernel(const int* __restrict__ batch, int* __restrict__ seg_start,
                              int mrows)
{
    const int sidx = blockIdx.x * blockDim.x + threadIdx.x;
    if (sidx > NSEG) return;
    int lo = 0, hi = mrows;
    while (lo < hi) {
        const int mid = (lo + hi) >> 1;
        if (batch[mid] < sidx) lo = mid + 1; else hi = mid;
    }
    seg_start[sidx] = lo;
}

// ---------------------------------------------------------------------------
// Kernel B2: per-segment max and sum(exp(s - max)). Block per segment.
// ---------------------------------------------------------------------------
__global__ __launch_bounds__(256) void stats_kernel(
    const float* __restrict__ s, const int* __restrict__ seg_start,
    float* __restrict__ seg_max, float* __restrict__ seg_sum)
{
    const int seg = blockIdx.x;
    const int beg = seg_start[seg], end = seg_start[seg + 1];
    const int t = threadIdx.x;

    float m = -INFINITY;
    for (int i = beg + t; i < end; i += 256) m = fmaxf(m, s[i]);
#pragma unroll
    for (int off = 32; off; off >>= 1) m = fmaxf(m, __shfl_down(m, off, 64));

    __shared__ float redm[4];
    __shared__ float reds[4];
    __shared__ float mbr;
    if ((t & 63) == 0) redm[t >> 6] = m;
    __syncthreads();
    if (t == 0) mbr = fmaxf(fmaxf(redm[0], redm[1]), fmaxf(redm[2], redm[3]));
    __syncthreads();
    m = mbr;

    float sum = 0.f;
    for (int i = beg + t; i < end; i += 256) sum += __expf(s[i] - m);
#pragma unroll
    for (int off = 32; off; off >>= 1) sum += __shfl_down(sum, off, 64);
    if ((t & 63) == 0) reds[t >> 6] = sum;
    __syncthreads();
    if (t == 0) {
        seg_max[seg] = m;
        seg_sum[seg] = reds[0] + reds[1] + reds[2] + reds[3];
    }
}

// ---------------------------------------------------------------------------
// Kernel C: pooled[seg] = sum_i w_i * x[i].  Block per segment, 4 waves:
// wave rq takes rows = rq (mod 4), lane dq takes dims [4dq, 4dq+4).
// w computed per 256-row chunk into LDS. Exclusive writer -> no init needed.
// ---------------------------------------------------------------------------
__global__ __launch_bounds__(256) void pool_kernel(
    const float* __restrict__ x, const float* __restrict__ s,
    const int* __restrict__ seg_start, const float* __restrict__ seg_max,
    const float* __restrict__ seg_sum, float* __restrict__ out)
{
    const int seg = blockIdx.x;
    const int beg = seg_start[seg], end = seg_start[seg + 1];
    const int t = threadIdx.x;
    const int dq = t & 63, rq = t >> 6;

    const float m = seg_max[seg];
    const float inv = 1.f / (seg_sum[seg] + 1e-16f);

    __shared__ __align__(16) float wl[256];
    __shared__ __align__(16) float red[256 * 4];

    v4f acc = {0.f, 0.f, 0.f, 0.f};
    for (int c0 = beg; c0 < end; c0 += 256) {
        const int cnt = min(256, end - c0);
        __syncthreads();
        if (t < cnt) wl[t] = __expf(s[c0 + t] - m) * inv;
        __syncthreads();
#pragma unroll 4
        for (int ii = 0; ii < cnt; ii += 4) {
            const int r = ii + rq;            // wave-uniform guard
            if (r < cnt) {
                const float wv = wl[r];
                const v4f xv = *(const v4f*)(x + (size_t)(c0 + r) * KDIM + dq * 4);
                acc += wv * xv;
            }
        }
    }

    *(v4f*)&red[t * 4] = acc;
    __syncthreads();
    if (t < 64) {
        v4f tot = *(v4f*)&red[t * 4];
        tot += *(v4f*)&red[(t + 64) * 4];
        tot += *(v4f*)&red[(t + 128) * 4];
        tot += *(v4f*)&red[(t + 192) * 4];
        *(v4f*)(out + (size_t)seg * KDIM + t * 4) = tot;
    }
}

// ---------------------------------------------------------------------------
extern "C" void kernel_launch(void* const* d_in, const int* in_sizes, int n_in,
                              void* d_out, int out_size, void* d_ws, size_t ws_size,
                              hipStream_t stream)
{
    const float* x   = (const float*)d_in[0];
    const int* batch = (const int*)d_in[1];
    const float* W1  = (const float*)d_in[2];
    const float* b1  = (const float*)d_in[3];
    const float* W2  = (const float*)d_in[4];
    const float* b2  = (const float*)d_in[5];
    float* out = (float*)d_out;

    const int mrows = in_sizes[0] / KDIM;  // 1,000,000

    char* ws = (char*)d_ws;
    float* s       = (float*)ws;                   // mrows * 4 B
    int* seg_start = (int*)(ws + 4000000);         // 1025 * 4 B
    float* seg_max = (float*)(ws + 4004112);       // 1024 * 4 B
    float* seg_sum = (float*)(ws + 4008224);       // 1024 * 4 B

    scores_kernel<<<512, 512, 0, stream>>>(x, W1, b1, W2, b2, s, mrows);
    bounds_kernel<<<5, 256, 0, stream>>>(batch, seg_start, mrows);
    stats_kernel<<<NSEG, 256, 0, stream>>>(s, seg_start, seg_max, seg_sum);
    pool_kernel<<<NSEG, 256, 0, stream>>>(x, s, seg_start, seg_max, seg_sum, out);
}